// Round 6
// baseline (14071.266 us; speedup 1.0000x reference)
//
#include <hip/hip_runtime.h>
#include <math.h>

#define HD 1024
#define BB 256
#define NCAM 15
#define TT 60
#define G3 3072
#define LDW 36      // f32 LDS stride for gi kernel
#define NS 24       // samples per pass, gi kernel

typedef _Float16 f16x8 __attribute__((ext_vector_type(8)));
typedef float f32x4 __attribute__((ext_vector_type(4)));

__device__ __forceinline__ unsigned short f2h(float f) {
    _Float16 h = (_Float16)f;             // v_cvt_f16_f32, RNE
    unsigned short u;
    __builtin_memcpy(&u, &h, 2);
    return u;
}
__device__ __forceinline__ float sigf(float v) { return 1.f / (1.f + expf(-v)); }

// bounded relaxed spin (R5-verified protocol); caller fences after
__device__ __forceinline__ void wait_ge(int* ctr, int target) {
    int guard = 0;
    while (__hip_atomic_load(ctr, __ATOMIC_RELAXED, __HIP_MEMORY_SCOPE_AGENT) < target) {
        __builtin_amdgcn_s_sleep(2);
        if (++guard > (1 << 20)) break;   // failsafe: never hang the harness
    }
}

// ---------------- grouping ----------------
__global__ void group_kernel(const int* __restrict__ cam,
                             int* __restrict__ off, int* __restrict__ list) {
    __shared__ int cnt[NCAM];
    __shared__ int soff[NCAM + 1];
    int tid = threadIdx.x;
    if (tid < NCAM) cnt[tid] = 0;
    __syncthreads();
    int c = cam[tid];
    int pos = atomicAdd(&cnt[c], 1);
    __syncthreads();
    if (tid == 0) {
        soff[0] = 0;
        for (int i = 0; i < NCAM; ++i) soff[i + 1] = soff[i] + cnt[i];
    }
    __syncthreads();
    list[soff[c] + pos] = tid;
    if (tid <= NCAM) off[tid] = soff[tid];
}

// ---------------- per-camera input projection (f32, unchanged) ----------------
__global__ __launch_bounds__(256) void gi_gemm_kernel(
    const float* __restrict__ W_ih, const float* __restrict__ b_ih,
    const float* __restrict__ b_hh, const float* __restrict__ x,
    const int* __restrict__ off, const int* __restrict__ list,
    float* __restrict__ gi) {
    int c  = blockIdx.x;
    int r0 = blockIdx.y * 96;
    int tid = threadIdx.x;
    int tx = tid & 7, ty = tid >> 3;

    __shared__ __align__(16) float wlds[96 * LDW];
    __shared__ __align__(16) float hlds[NS * LDW];
    __shared__ int slist[NS];

    int base = off[c];
    int nc = off[c + 1] - base;

    for (int s0 = 0; s0 < nc; s0 += NS) {
        __syncthreads();
        if (tid < NS) slist[tid] = (s0 + tid < nc) ? list[base + s0 + tid] : -1;
        __syncthreads();

        float acc[3][3];
#pragma unroll
        for (int g = 0; g < 3; ++g)
#pragma unroll
            for (int q = 0; q < 3; ++q) acc[g][q] = 0.f;

        for (int k0 = 0; k0 < HD; k0 += 32) {
#pragma unroll
            for (int i = 0; i < 3; ++i) {
                int idx = tid + 256 * i;
                int row = idx >> 3, col4 = idx & 7;
                float4 w = *(const float4*)(W_ih +
                    ((size_t)c * G3 + r0 + row) * HD + k0 + col4 * 4);
                *(float4*)(wlds + row * LDW + col4 * 4) = w;
            }
            {
                int s = tid >> 3, col4 = tid & 7;
                if (s < NS) {
                    int b = slist[s];
                    float4 hv = make_float4(0.f, 0.f, 0.f, 0.f);
                    if (b >= 0)
                        hv = *(const float4*)(x + (size_t)b * HD + k0 + col4 * 4);
                    *(float4*)(hlds + s * LDW + col4 * 4) = hv;
                }
            }
            __syncthreads();
#pragma unroll
            for (int kk = 0; kk < 32; kk += 4) {
                float4 w0 = *(const float4*)(wlds + (0 * 32 + ty) * LDW + kk);
                float4 w1 = *(const float4*)(wlds + (1 * 32 + ty) * LDW + kk);
                float4 w2 = *(const float4*)(wlds + (2 * 32 + ty) * LDW + kk);
#pragma unroll
                for (int q = 0; q < 3; ++q) {
                    float4 hv = *(const float4*)(hlds + (tx + 8 * q) * LDW + kk);
                    acc[0][q] += w0.x * hv.x + w0.y * hv.y + w0.z * hv.z + w0.w * hv.w;
                    acc[1][q] += w1.x * hv.x + w1.y * hv.y + w1.z * hv.z + w1.w * hv.w;
                    acc[2][q] += w2.x * hv.x + w2.y * hv.y + w2.z * hv.z + w2.w * hv.w;
                }
            }
            __syncthreads();
        }
#pragma unroll
        for (int q = 0; q < 3; ++q) {
            int b = slist[tx + 8 * q];
            if (b >= 0) {
#pragma unroll
                for (int g = 0; g < 3; ++g) {
                    int R = r0 + g * 32 + ty;
                    float bias = b_ih[c * G3 + R];
                    if (R < 2 * HD) bias += b_hh[c * G3 + R];
                    gi[(size_t)b * G3 + R] = acc[g][q] + bias;
                }
            }
        }
    }
}

// ---------------- W_hh -> fp16 image prep (single plane, unchanged layout) ----------------
__global__ __launch_bounds__(256) void prep_kernel(
    const float* __restrict__ W_hh, unsigned short* __restrict__ Wimg) {
    int c = blockIdx.z, jt = blockIdx.y;
    int lin = blockIdx.x * 256 + threadIdx.x;   // [0, 12288) = 16 iters * 768 chunks
    int it  = lin / 768;
    int rem = lin - it * 768;
    int r = rem >> 3, kcp = rem & 7;
    int gate = r >> 5, jl = r & 31;
    int kc = kcp ^ (r & 7);
    int k = it * 64 + kc * 8;
    const float* src = W_hh + ((size_t)c * G3 + gate * HD + jt * 32 + jl) * HD + k;
    float4 v0 = *(const float4*)src;
    float4 v1 = *(const float4*)(src + 4);
    float v[8] = {v0.x, v0.y, v0.z, v0.w, v1.x, v1.y, v1.z, v1.w};
    unsigned int hp[4];
#pragma unroll
    for (int e = 0; e < 4; ++e) {
        unsigned short h0 = f2h(v[2 * e]), h1 = f2h(v[2 * e + 1]);
        hp[e] = (unsigned)h0 | ((unsigned)h1 << 16);
    }
    unsigned short* dst = Wimg + ((size_t)(c * 32 + jt) * 16 + it) * 6144 + r * 64 + kcp * 8;
    *(uint4*)dst = make_uint4(hp[0], hp[1], hp[2], hp[3]);
}

// ---------------- persistent gate-split recurrent kernel ----------------
// Grid (NCAM, 32, 3) = 1440 blocks x 128 thr, 0 LDS, <=170 VGPR
// (launch_bounds(128,3): 12 waves/CU -> 6 blocks/CU -> capacity 1536 >= 1440).
// Block (c,jt,g) holds gate g's 32x1024 weight tile in 32 f16x8 regs (128 VGPR).
// g<2 (r,z): MFMA -> post pre-activations to ps -> signal pf[c*32+jt].
// g==2 (n): spin pf -> MFMA -> read partials -> GRU epilogue -> signal arr[c].
// Transitive release/acquire: pf signal happens-after writer observed arr,
// so readers need only the pf spin. Protocol verbatim from R5 (HW-verified).
__global__ __launch_bounds__(128, 3) void persist_kernel(
    const unsigned short* __restrict__ Wimg, const float* __restrict__ b_hh,
    const float* __restrict__ gi, const int* __restrict__ off,
    const int* __restrict__ list, const unsigned short* __restrict__ hzero,
    unsigned short* __restrict__ hfA, unsigned short* __restrict__ hfB,
    float* __restrict__ hplane, float* __restrict__ ps,
    int* __restrict__ arr, int* __restrict__ pf, float* __restrict__ out) {
    int c  = blockIdx.x;
    int jt = blockIdx.y;
    int g  = blockIdx.z;
    int cj = c * 32 + jt;
    int tid = threadIdx.x;
    int lane = tid & 63;
    int w = tid >> 6;
    int l15 = lane & 15;
    int l4  = lane >> 4;

    // ---- one-time weight preload: 32 f16x8 frags (gate g rows, full K) ----
    f16x8 wreg[32];
    {
        const unsigned short* wbase = Wimg + (size_t)cj * 16 * 6144;
        int r = g * 32 + w * 16 + l15;
#pragma unroll
        for (int it = 0; it < 16; ++it)
#pragma unroll
            for (int kt = 0; kt < 2; ++kt) {
                int kcp = (kt * 4 + l4) ^ (r & 7);
                wreg[it * 2 + kt] =
                    *(const f16x8*)(wbase + (size_t)it * 6144 + r * 64 + kcp * 8);
            }
    }

    int base = off[c];
    int nc = off[c + 1] - base;
    int npass = (nc + 31) >> 5;

    int j = jt * 32 + w * 16 + l4 * 4;
    f32x4 bhn = *(const f32x4*)(b_hh + c * G3 + 2 * HD + j);
    int* arrc = arr + c;
    int* pfc  = pf + cj;
    float* myps = ps + (size_t)(cj * 2 + g) * 2048;      // writer tile (g<2)
    const float* ps0 = ps + (size_t)(cj * 2 + 0) * 2048; // reader views
    const float* ps1 = ps + (size_t)(cj * 2 + 1) * 2048;

    for (int t = 0; t < TT; ++t) {
        const unsigned short* hf_in = (t & 1) ? hfB : hfA;
        unsigned short*      hf_out = (t & 1) ? hfA : hfB;

        if (g < 2) {
            // ---------- writer: r/z gate pre-activations ----------
            if (t) {
                if (tid == 0) wait_ge(arrc, 32 * t);
                __syncthreads();
                __threadfence();   // acquire: h planes for step t
            }
#pragma unroll
            for (int p = 0; p < 2; ++p) {
                if (p < npass) {
                    int s0 = p * 32;
                    int sv = -1;
                    if (lane < 32) sv = (s0 + lane < nc) ? list[base + s0 + lane] : -1;
                    int nq = ((nc - s0) > 16) ? 2 : 1;
                    const unsigned short* bb[2];
#pragma unroll
                    for (int q = 0; q < 2; ++q) {
                        int b = __shfl(sv, q * 16 + l15);
                        bb[q] = (b >= 0) ? hf_in + (size_t)b * HD : hzero;
                    }
                    f32x4 acc[2];
                    acc[0] = (f32x4){0.f, 0.f, 0.f, 0.f};
                    acc[1] = (f32x4){0.f, 0.f, 0.f, 0.f};
#pragma unroll
                    for (int it = 0; it < 16; ++it)
#pragma unroll
                        for (int kt = 0; kt < 2; ++kt) {
                            int koff = it * 64 + (kt * 4 + l4) * 8;
                            f16x8 b0 = *(const f16x8*)(bb[0] + koff);
                            acc[0] = __builtin_amdgcn_mfma_f32_16x16x32_f16(
                                wreg[it * 2 + kt], b0, acc[0], 0, 0, 0);
                            if (nq > 1) {
                                f16x8 b1 = *(const f16x8*)(bb[1] + koff);
                                acc[1] = __builtin_amdgcn_mfma_f32_16x16x32_f16(
                                    wreg[it * 2 + kt], b1, acc[1], 0, 0, 0);
                            }
                        }
                    float* d = myps + (size_t)((p * 128 + tid) * 2) * 4;
                    *(f32x4*)d = acc[0];
                    *(f32x4*)(d + 4) = acc[1];
                }
            }
            __threadfence();   // release partials
            __syncthreads();
            if (tid == 0)
                __hip_atomic_fetch_add(pfc, 1, __ATOMIC_RELAXED, __HIP_MEMORY_SCOPE_AGENT);
        } else {
            // ---------- reader: n gate + GRU epilogue ----------
            if (tid == 0) wait_ge(pfc, 2 * (t + 1));
            __syncthreads();
            __threadfence();   // acquire: partials + h planes (transitive)
#pragma unroll
            for (int p = 0; p < 2; ++p) {
                if (p < npass) {
                    int s0 = p * 32;
                    int sv = -1;
                    if (lane < 32) sv = (s0 + lane < nc) ? list[base + s0 + lane] : -1;
                    int nq = ((nc - s0) > 16) ? 2 : 1;
                    int bidx[2];
                    const unsigned short* bb[2];
#pragma unroll
                    for (int q = 0; q < 2; ++q) {
                        bidx[q] = __shfl(sv, q * 16 + l15);
                        bb[q] = (bidx[q] >= 0) ? hf_in + (size_t)bidx[q] * HD : hzero;
                    }
                    f32x4 acc[2];
                    acc[0] = (f32x4){0.f, 0.f, 0.f, 0.f};
                    acc[1] = (f32x4){0.f, 0.f, 0.f, 0.f};
#pragma unroll
                    for (int it = 0; it < 16; ++it)
#pragma unroll
                        for (int kt = 0; kt < 2; ++kt) {
                            int koff = it * 64 + (kt * 4 + l4) * 8;
                            f16x8 b0 = *(const f16x8*)(bb[0] + koff);
                            acc[0] = __builtin_amdgcn_mfma_f32_16x16x32_f16(
                                wreg[it * 2 + kt], b0, acc[0], 0, 0, 0);
                            if (nq > 1) {
                                f16x8 b1 = *(const f16x8*)(bb[1] + koff);
                                acc[1] = __builtin_amdgcn_mfma_f32_16x16x32_f16(
                                    wreg[it * 2 + kt], b1, acc[1], 0, 0, 0);
                            }
                        }
#pragma unroll
                    for (int q = 0; q < 2; ++q) {
                        int b = bidx[q];
                        if (q < nq && b >= 0) {
                            size_t po = (size_t)((p * 128 + tid) * 2 + q) * 4;
                            f32x4 p0 = *(const f32x4*)(ps0 + po);   // gh_r
                            f32x4 p1 = *(const f32x4*)(ps1 + po);   // gh_z
                            const float* gib = gi + (size_t)b * G3;
                            f32x4 gr = *(const f32x4*)(gib + j);
                            f32x4 gz = *(const f32x4*)(gib + HD + j);
                            f32x4 gn = *(const f32x4*)(gib + 2 * HD + j);
                            f32x4 hp = *(const f32x4*)(hplane + (size_t)b * HD + j);
                            f32x4 hn;
#pragma unroll
                            for (int e = 0; e < 4; ++e) {
                                float r = sigf(gr[e] + p0[e]);
                                float z = sigf(gz[e] + p1[e]);
                                float n = tanhf(gn[e] + r * (acc[q][e] + bhn[e]));
                                hn[e] = (1.f - z) * n + z * hp[e];
                                out[((size_t)(b * HD + j + e)) * TT + t] = hn[e];
                            }
                            *(f32x4*)(hplane + (size_t)b * HD + j) = hn;
                            unsigned int hw[2];
#pragma unroll
                            for (int e = 0; e < 2; ++e) {
                                unsigned short h0 = f2h(hn[2 * e]), h1 = f2h(hn[2 * e + 1]);
                                hw[e] = (unsigned)h0 | ((unsigned)h1 << 16);
                            }
                            *(uint2*)(hf_out + (size_t)b * HD + j) = make_uint2(hw[0], hw[1]);
                        }
                    }
                }
            }
            __threadfence();   // release h planes
            __syncthreads();
            if (tid == 0)
                __hip_atomic_fetch_add(arrc, 1, __ATOMIC_RELAXED, __HIP_MEMORY_SCOPE_AGENT);
        }
    }
}

extern "C" void kernel_launch(void* const* d_in, const int* in_sizes, int n_in,
                              void* d_out, int out_size, void* d_ws, size_t ws_size,
                              hipStream_t stream) {
    const float* x    = (const float*)d_in[0];
    const int*   cam  = (const int*)d_in[1];
    const float* W_ih = (const float*)d_in[2];
    const float* W_hh = (const float*)d_in[3];
    const float* b_ih = (const float*)d_in[4];
    const float* b_hh = (const float*)d_in[5];
    float* out = (float*)d_out;

    char* ws = (char*)d_ws;
    int*   off   = (int*)ws;                               // 64 B
    int*   list  = (int*)(ws + 64);                        // 1 KB
    int*   arr   = (int*)(ws + 2048);                      // 64 B per-cam arrival
    int*   pf    = (int*)(ws + 2112);                      // 1920 B per-(c,jt) partial flags
    unsigned short* hzero = (unsigned short*)(ws + 4096);  // 2 KB zeros
    float* gi    = (float*)(ws + 8192);                    // 3 MB
    float* hplane = (float*)(ws + 3153920);                // 1 MB f32 h state
    unsigned short* hfA = (unsigned short*)(ws + 4202496); // 512 KB fp16 h plane
    unsigned short* hfB = (unsigned short*)(ws + 4726784); // 512 KB fp16 h plane
    float* ps    = (float*)(ws + 5251072);                 // 7.86 MB partial exchange
    unsigned short* Wimg = (unsigned short*)(ws + 13115392); // 94.4 MB fp16 image

    group_kernel<<<1, 256, 0, stream>>>(cam, off, list);
    gi_gemm_kernel<<<dim3(NCAM, G3 / 96), 256, 0, stream>>>(
        W_ih, b_ih, b_hh, x, off, list, gi);
    prep_kernel<<<dim3(48, 32, NCAM), 256, 0, stream>>>(W_hh, Wimg);
    hipMemsetAsync(ws + 2048, 0, 2048, stream);            // arr + pf (per-replay reset)
    hipMemsetAsync(hzero, 0, 2048, stream);
    hipMemsetAsync(hplane, 0, (size_t)BB * HD * sizeof(float), stream);
    hipMemsetAsync(hfA, 0, (size_t)BB * HD * sizeof(short), stream);

    persist_kernel<<<dim3(NCAM, 32, 3), 128, 0, stream>>>(
        Wimg, b_hh, gi, off, list, hzero, hfA, hfB, hplane, ps, arr, pf, out);
}